// Round 2
// baseline (509.784 us; speedup 1.0000x reference)
//
#include <hip/hip_runtime.h>
#include <math.h>

#define NPROP 2000
#define CHUNK 256                 // proposals per staging chunk (== blockDim)
#define NCHUNK ((NPROP + CHUNK - 1) / CHUNK)   // 8
#define RPN_ROW (NPROP * 5)       // 10000 floats
#define SC_ROW  (NPROP * 2)       // 4000 floats
#define PANELTY_K 0.055f
#define HANN_W 0.42f
#define PI_F 3.14159265358979323846f

// One block per row. Coalesced global loads -> LDS -> stride-5 gather in LDS
// (2 lanes/bank on 32 banks = conflict-free per m136).
__global__ __launch_bounds__(256) void trnms_kernel(
    const float* __restrict__ rois,      // (N,4)
    const float* __restrict__ rpn,       // (N,NPROP,5)
    const float* __restrict__ scores,    // (N,NPROP,2)
    float* __restrict__ out_rois,        // (N,4)
    float* __restrict__ out_scores)      // (N,1)
{
    const int i   = blockIdx.x;
    const int tid = threadIdx.x;

    __shared__ float lds_rpn[CHUNK * 5];   // 5120 B
    __shared__ float lds_sc [CHUNK * 2];   // 2048 B

    // Reference ROI stats (identical expression order to numpy reference)
    const float rx1 = rois[i * 4 + 0], ry1 = rois[i * 4 + 1];
    const float rx2 = rois[i * 4 + 2], ry2 = rois[i * 4 + 3];
    const float x = (rx1 + rx2) * 0.5f;
    const float y = (ry1 + ry2) * 0.5f;
    const float w = fabsf(rx1 - rx2) + 0.0001f;
    const float h = fabsf(ry1 - ry2) + 0.0001f;
    const float p = (w + h) * 0.5f;
    const float s = sqrtf((w + p) * (h + p));
    const float ratio = w / h;
    const float r_max = fmaxf(ratio, 1.0f / ratio);
    const float window = s * 2.0f;

    const float* __restrict__ rowr  = rpn    + (long long)i * RPN_ROW;
    const float* __restrict__ rowsc = scores + (long long)i * SC_ROW;

    float best  = -INFINITY;
    int   besti = 0x7fffffff;

    for (int c = 0; c < NCHUNK; ++c) {
        // ---- coalesced stride-1 loads of this chunk into registers ----
        const int rbase = c * (CHUNK * 5);   // dword offset into rpn row
        const int sbase = c * (CHUNK * 2);   // dword offset into scores row
        float rreg[5], sreg[2];
        #pragma unroll
        for (int k = 0; k < 5; ++k) {
            const int idx = rbase + k * CHUNK + tid;
            rreg[k] = (idx < RPN_ROW) ? rowr[idx] : 0.0f;
        }
        #pragma unroll
        for (int k = 0; k < 2; ++k) {
            const int idx = sbase + k * CHUNK + tid;
            sreg[k] = (idx < SC_ROW) ? rowsc[idx] : 0.0f;
        }

        __syncthreads();   // previous chunk's compute done before overwrite
        #pragma unroll
        for (int k = 0; k < 5; ++k) lds_rpn[k * CHUNK + tid] = rreg[k];
        #pragma unroll
        for (int k = 0; k < 2; ++k) lds_sc [k * CHUNK + tid] = sreg[k];
        __syncthreads();

        // ---- compute this thread's proposal from LDS ----
        const int j = c * CHUNK + tid;
        if (j < NPROP) {
            const float px1 = lds_rpn[tid * 5 + 1];
            const float py1 = lds_rpn[tid * 5 + 2];
            const float px2 = lds_rpn[tid * 5 + 3];
            const float py2 = lds_rpn[tid * 5 + 4];
            const float scj = lds_sc [tid * 2 + 1];

            const float x_ = (px1 + px2) * 0.5f;
            const float y_ = (py1 + py2) * 0.5f;
            const float w_ = fabsf(px1 - px2) + 0.0001f;
            const float h_ = fabsf(py1 - py2) + 0.0001f;
            const float p_ = (w_ + h_) * 0.5f;
            const float s_ = sqrtf((w_ + p_) * (h_ + p_));
            const float smax = fmaxf(s / s_, s_ / s);
            const float pen  = expf(-PANELTY_K * (smax * r_max - 1.0f));
            const float dx = x - x_;
            const float dy = y - y_;
            const float dist = sqrtf(dx * dx + dy * dy);
            float han = 0.5f + 0.5f * cosf(dist * PI_F / window);
            han = (dist > window) ? 0.0f : han;
            const float val = scj * pen + han * HANN_W;
            if (val > best || (val == best && j < besti)) { best = val; besti = j; }
        }
    }

    // ---- wave-level reduction (64 lanes), first-index tie-break ----
    #pragma unroll
    for (int off = 32; off > 0; off >>= 1) {
        const float ov = __shfl_down(best, off);
        const int   oi = __shfl_down(besti, off);
        if (ov > best || (ov == best && oi < besti)) { best = ov; besti = oi; }
    }

    __shared__ float sval[4];
    __shared__ int   sidx[4];
    const int wave = tid >> 6;
    if ((tid & 63) == 0) { sval[wave] = best; sidx[wave] = besti; }
    __syncthreads();

    if (tid == 0) {
        #pragma unroll
        for (int k = 1; k < 4; ++k) {
            const float ov = sval[k];
            const int   oi = sidx[k];
            if (ov > best || (ov == best && oi < besti)) { best = ov; besti = oi; }
        }
        out_rois[i * 4 + 0] = rowr[besti * 5 + 1];
        out_rois[i * 4 + 1] = rowr[besti * 5 + 2];
        out_rois[i * 4 + 2] = rowr[besti * 5 + 3];
        out_rois[i * 4 + 3] = rowr[besti * 5 + 4];
        out_scores[i] = rowsc[besti * 2 + 1];
    }
}

extern "C" void kernel_launch(void* const* d_in, const int* in_sizes, int n_in,
                              void* d_out, int out_size, void* d_ws, size_t ws_size,
                              hipStream_t stream) {
    const float* rois   = (const float*)d_in[0];  // (N,4)
    const float* rpn    = (const float*)d_in[1];  // (N,2000,5)
    const float* scores = (const float*)d_in[2];  // (N,2000,2)

    const int N = in_sizes[0] / 4;  // 8192

    float* out_rois   = (float*)d_out;          // first N*4 floats
    float* out_scores = (float*)d_out + N * 4;  // next N floats

    trnms_kernel<<<N, 256, 0, stream>>>(rois, rpn, scores, out_rois, out_scores);
}